// Round 12
// baseline (725.233 us; speedup 1.0000x reference)
//
#include <hip/hip_runtime.h>
#include <hip/hip_cooperative_groups.h>

namespace cg = cooperative_groups;

// Problem constants (fixed by the reference)
#define VOCAB 50000
#define D     300
#define B_    64
#define LC    32
#define T_    256
#define LT    64
#define NSEL  5
#define NCAND 16              // noisy-candidate buffer for exact rescoring

#define A_U4   2560
#define A_HALF 20480
#define TROW   320            // hi-ONLY table row: 320 halfs = 640 B = 10 lines

typedef _Float16 half8_t __attribute__((ext_vector_type(8)));
typedef float    f32x4   __attribute__((ext_vector_type(4)));

// Session ledger:
//  R1/R3: register-spill walls -> 16 waves/CU @ 128 regs is THE point.
//  R2: setprio +4% cost. R5: serve-rate law dur = FETCH/3.3TB/s (all configs).
//  R7: 64B fill granule. R8: alignment is the table's value.
//  R9: f16-hi selection rows + exact top-16 rescore: k_scores 103us. int8/fp8
//      further step is numerically dead (score noise >> rank gaps).
//  R10: parallel rescore: 235us. R11: k_prep block-count null -> tail is
//      per-LAUNCH overhead (~15us/dispatch) + fixed floor (~75-90us).
//  R12 (this): fuse ALL phases into one cooperative kernel (grid 1024 = fully
//      resident, grid.sync between phases). Synchronous-error fallback to the
//      R10 4-kernel path. Arithmetic bitwise-identical: absmax must stay 2^-10.

// hi/lo split of a float4 pair into half8 hi and half8 lo (exact path)
__device__ __forceinline__ void split8(const float4& a, const float4& b,
                                       half8_t& hv, half8_t& lv) {
    float x[8] = {a.x, a.y, a.z, a.w, b.x, b.y, b.z, b.w};
#pragma unroll
    for (int i = 0; i < 8; ++i) {
        _Float16 h = (_Float16)x[i];
        hv[i] = h;
        lv[i] = (_Float16)(x[i] - (float)h);
    }
}

// ---------------- exact K-loop (f32 emb gather + on-the-fly split) -----------
template<int NI>
__device__ __forceinline__ void compute_exact(const uint4* sA,
                                              const float* __restrict__ emb,
                                              const int* __restrict__ trow, int lcol0,
                                              int lane, f32x4 acc[2][NI]) {
    int ln = lane & 15, quad = lane >> 4;
#pragma unroll
    for (int mi = 0; mi < 2; ++mi)
#pragma unroll
        for (int ni = 0; ni < NI; ++ni) acc[mi][ni] = (f32x4)0.0f;

    int arow0 = ln * 40;
    int arow1 = (16 + ln) * 40;
    int key = ln & 7;
    int qo = quad * 8;

    const float* bp[NI];
#pragma unroll
    for (int ni = 0; ni < NI; ++ni) {
        int tok = trow[lcol0 + ni * 16 + ln];
        bp[ni] = emb + (size_t)tok * D;
    }
#pragma unroll 1
    for (int ks = 0; ks < 10; ++ks) {
        int kb = ks * 32 + qo;
        int ka = kb > 296 ? 296 : kb;
        int kb4 = kb + 4;
        int kbb = kb4 > 296 ? 296 : kb4;
        float4 b0[NI], b1[NI];
#pragma unroll
        for (int ni = 0; ni < NI; ++ni) {
            b0[ni] = *(const float4*)(bp[ni] + ka);
            b1[ni] = *(const float4*)(bp[ni] + kbb);
        }
        if (kb >= 296) {
            float4 z = make_float4(0.f, 0.f, 0.f, 0.f);
#pragma unroll
            for (int ni = 0; ni < NI; ++ni) {
                if (kb >= 300) b0[ni] = z;
                b1[ni] = z;
            }
        }
        int sp = (ks * 4 + quad) ^ key;
        half8_t ah[2], al[2];
        ah[0] = __builtin_bit_cast(half8_t, sA[arow0 + sp]);
        al[0] = __builtin_bit_cast(half8_t, sA[1280 + arow0 + sp]);
        ah[1] = __builtin_bit_cast(half8_t, sA[arow1 + sp]);
        al[1] = __builtin_bit_cast(half8_t, sA[1280 + arow1 + sp]);
        half8_t bh[NI], bl[NI];
#pragma unroll
        for (int ni = 0; ni < NI; ++ni) split8(b0[ni], b1[ni], bh[ni], bl[ni]);
#pragma unroll
        for (int mi = 0; mi < 2; ++mi)
#pragma unroll
            for (int ni = 0; ni < NI; ++ni) {
                acc[mi][ni] = __builtin_amdgcn_mfma_f32_16x16x32_f16(ah[mi], bh[ni], acc[mi][ni], 0, 0, 0);
                acc[mi][ni] = __builtin_amdgcn_mfma_f32_16x16x32_f16(ah[mi], bl[ni], acc[mi][ni], 0, 0, 0);
                acc[mi][ni] = __builtin_amdgcn_mfma_f32_16x16x32_f16(al[mi], bh[ni], acc[mi][ni], 0, 0, 0);
            }
    }
}

// ---------------- noisy K-loop (hi-only 640B table rows, selection only) -----
__device__ __forceinline__ void compute_noisy(const uint4* sA,
                                              const _Float16* __restrict__ tab,
                                              const int* __restrict__ trow,
                                              int lane, f32x4 acc[2][4]) {
    int ln = lane & 15, quad = lane >> 4;
#pragma unroll
    for (int mi = 0; mi < 2; ++mi)
#pragma unroll
        for (int ni = 0; ni < 4; ++ni) acc[mi][ni] = (f32x4)0.0f;

    int arow0 = ln * 40;
    int arow1 = (16 + ln) * 40;
    int key = ln & 7;
    int qo = quad * 8;

    const _Float16* rp[4];
#pragma unroll
    for (int ni = 0; ni < 4; ++ni) {
        int tok = trow[ni * 16 + ln];
        rp[ni] = tab + (size_t)tok * TROW;
    }
    half8_t bh[2][4];
#pragma unroll
    for (int ni = 0; ni < 4; ++ni) bh[0][ni] = *(const half8_t*)(rp[ni] + qo);
#pragma unroll
    for (int ks = 0; ks < 10; ++ks) {
        int cur = ks & 1, nxt = cur ^ 1;
        if (ks < 9) {
            int ko = (ks + 1) * 32 + qo;
#pragma unroll
            for (int ni = 0; ni < 4; ++ni)
                bh[nxt][ni] = *(const half8_t*)(rp[ni] + ko);
        }
        int sp = (ks * 4 + quad) ^ key;
        half8_t ah[2], al[2];
        ah[0] = __builtin_bit_cast(half8_t, sA[arow0 + sp]);
        al[0] = __builtin_bit_cast(half8_t, sA[1280 + arow0 + sp]);
        ah[1] = __builtin_bit_cast(half8_t, sA[arow1 + sp]);
        al[1] = __builtin_bit_cast(half8_t, sA[1280 + arow1 + sp]);
#pragma unroll
        for (int mi = 0; mi < 2; ++mi)
#pragma unroll
            for (int ni = 0; ni < 4; ++ni) {
                acc[mi][ni] = __builtin_amdgcn_mfma_f32_16x16x32_f16(ah[mi], bh[cur][ni], acc[mi][ni], 0, 0, 0);
                acc[mi][ni] = __builtin_amdgcn_mfma_f32_16x16x32_f16(al[mi], bh[cur][ni], acc[mi][ni], 0, 0, 0);
            }
    }
}

__device__ __forceinline__ float xmax4(float v) {
    v = fmaxf(v, __shfl_xor(v, 1)); v = fmaxf(v, __shfl_xor(v, 2));
    v = fmaxf(v, __shfl_xor(v, 4)); v = fmaxf(v, __shfl_xor(v, 8));
    return v;
}
__device__ __forceinline__ float xsum4(float v) {
    v += __shfl_xor(v, 1); v += __shfl_xor(v, 2);
    v += __shfl_xor(v, 4); v += __shfl_xor(v, 8);
    return v;
}

// target score from a wave's acc[2][4] — op order identical to R0..R11.
__device__ __forceinline__ float score_from_acc(f32x4 acc[2][4]) {
    float score_l[4] = {0.f, 0.f, 0.f, 0.f};
#pragma unroll
    for (int mi = 0; mi < 2; ++mi)
#pragma unroll
        for (int r = 0; r < 4; ++r) {
            float m = fmaxf(fmaxf(acc[mi][0][r], acc[mi][1][r]),
                            fmaxf(acc[mi][2][r], acc[mi][3][r]));
            m = xmax4(m);
            float p[4], s = 0.f;
#pragma unroll
            for (int ni = 0; ni < 4; ++ni) { p[ni] = __expf(acc[mi][ni][r] - m); s += p[ni]; }
            s = xsum4(s);
            float rv = 1.0f / s;
#pragma unroll
            for (int ni = 0; ni < 4; ++ni) score_l[ni] = fmaxf(score_l[ni], p[ni] * rv);
        }
    float tot = 0.f;
#pragma unroll
    for (int ni = 0; ni < 4; ++ni) {
        float v = score_l[ni];
        v = fmaxf(v, __shfl_xor(v, 16));
        v = fmaxf(v, __shfl_xor(v, 32));
        tot += v;
    }
    return xsum4(tot);
}

// ============== FUSED cooperative kernel: prep | scores | rescore | output ===
__global__ __launch_bounds__(256, 4) void k_fused(const int* __restrict__ claim,
                                                  const int* __restrict__ targets,
                                                  const float* __restrict__ emb,
                                                  _Float16* __restrict__ tab,
                                                  _Float16* __restrict__ wsA,
                                                  float* __restrict__ wsScr,
                                                  int* __restrict__ wsCand,
                                                  float* __restrict__ wsScoreC,
                                                  float* __restrict__ out) {
    cg::grid_group grid = cg::this_grid();
    __shared__ __align__(16) uint4 sA[A_U4];           // exactly 40960 B
    int wg = blockIdx.x, tid = threadIdx.x;
    int lane = tid & 63, wave = tid >> 6;

    // ---- phase 1: hi-only table (grid-stride) + claim A-images -------------
    for (int r = wg * 4 + wave; r < VOCAB; r += 4096) {
        const float* src = emb + (size_t)r * D;
        _Float16* d = tab + (size_t)r * TROW;
#pragma unroll
        for (int i = 0; i < 5; ++i) {
            int k = lane + i * 64;
            d[k] = (k < D) ? (_Float16)src[k] : (_Float16)0.0f;
        }
    }
    if (wg < 512) {
        int row = wg * 4 + wave;                       // 0..2047
        int b = row >> 5, m = row & 31;
        int tok = claim[row];
        const float* src = emb + (size_t)tok * D;
        _Float16* base = wsA + (size_t)b * A_HALF;
#pragma unroll
        for (int i = 0; i < 5; ++i) {
            int k = lane + i * 64;
            float x = (k < D) ? src[k] : 0.0f;
            _Float16 h = (_Float16)x;
            int sp = ((k >> 3) ^ (m & 7));
            int idx = (m * 40 + sp) * 8 + (k & 7);
            base[idx] = h;
            base[10240 + idx] = (_Float16)(x - (float)h);
        }
    }
    grid.sync();

    // ---- phase 2: noisy scores. 1024 blocks x 4 t-group iterations ---------
    {
        int xcd = wg & 7, rest = wg >> 3;              // rest 0..127
        int b = xcd * 8 + (rest >> 4);
        int tg4 = rest & 15;
        {
            const uint4* src = (const uint4*)(wsA + (size_t)b * A_HALF);
            for (int i = tid; i < A_U4; i += 256) sA[i] = src[i];
        }
        __syncthreads();
        for (int it = 0; it < 4; ++it) {
            int t = (tg4 * 4 + it) * 4 + wave;
            const int* trow = targets + ((size_t)b * T_ + t) * LT;
            f32x4 acc[2][4];
            compute_noisy(sA, tab, trow, lane, acc);
            float tot = score_from_acc(acc);
            if (lane == 0) wsScr[b * T_ + t] = tot;
        }
    }
    grid.sync();

    // ---- phase 3: exact rescore of noisy top-16 (blocks 0..255) ------------
    if (wg < 256) {
        int r = wg & 3, b = wg >> 2;
        {
            const uint4* src = (const uint4*)(wsA + (size_t)b * A_HALF);
            for (int i = tid; i < A_U4; i += 256) sA[i] = src[i];
        }
        // per-wave in-register replay of the noisy top-16 (rules == R10)
        float v[4];
#pragma unroll
        for (int i = 0; i < 4; ++i) v[i] = wsScr[b * T_ + lane + 64 * i];
        int myc = r * 4 + wave, myT = 0;
        for (int s = 0; s < NCAND; ++s) {
            float bv = v[0]; int bi = lane;
#pragma unroll
            for (int i = 1; i < 4; ++i) {
                int idx = lane + 64 * i;
                if (v[i] > bv) { bv = v[i]; bi = idx; }
            }
            for (int off = 32; off > 0; off >>= 1) {
                float ov = __shfl_down(bv, off);
                int   oi = __shfl_down(bi, off);
                if (ov > bv || (ov == bv && oi < bi)) { bv = ov; bi = oi; }
            }
            bi = __shfl(bi, 0);
            if (s == myc) myT = bi;
            if (r == 0 && wave == 0 && lane == 0) wsCand[b * NCAND + s] = bi;
            if ((bi & 63) == lane) v[bi >> 6] = -1e30f;
        }
        __syncthreads();                               // staging complete
        const int* trow = targets + ((size_t)b * T_ + myT) * LT;
        f32x4 acc[2][4];
        compute_exact<4>(sA, emb, trow, 0, lane, acc);
        float tot = score_from_acc(acc);
        if (lane == 0) wsScoreC[b * NCAND + myc] = tot;
    }
    grid.sync();

    // ---- phase 4: rank-j selection + exact tile + L2-normalize (0..319) ----
    if (wg < 320) {
        int b = wg / NSEL, j = wg % NSEL;
        {
            const uint4* src = (const uint4*)(wsA + (size_t)b * A_HALF);
            for (int i = tid; i < A_U4; i += 256) sA[i] = src[i];
        }
        // redundant per-thread selection from the 16 (cand,score) pairs
        unsigned used = 0; int sel = 0;
        for (int jj = 0; jj <= j; ++jj) {
            float bs = -1e30f; int bt = 0x7fffffff, bsl = 0;
            for (int s = 0; s < NCAND; ++s) {
                if (used & (1u << s)) continue;
                float sc = wsScoreC[b * NCAND + s];
                int tt = wsCand[b * NCAND + s];
                if (sc > bs || (sc == bs && tt < bt)) { bs = sc; bt = tt; bsl = s; }
            }
            used |= (1u << bsl);
            sel = bt;
        }
        __syncthreads();                               // staging complete
        const int* trow = targets + ((size_t)b * T_ + sel) * LT;
        f32x4 acc[2][1];
        compute_exact<1>(sA, emb, trow, wave * 16, lane, acc);

        int ln = lane & 15, quad = lane >> 4;
        float pv[2][4];
#pragma unroll
        for (int mi = 0; mi < 2; ++mi)
#pragma unroll
            for (int r = 0; r < 4; ++r) {
                float vv = acc[mi][0][r] * acc[mi][0][r];
                pv[mi][r] = xsum4(vv);
            }
        __syncthreads();                               // all sA reads done
        float* sS = (float*)sA;                        // overlay in dead sA
#pragma unroll
        for (int mi = 0; mi < 2; ++mi)
#pragma unroll
            for (int r = 0; r < 4; ++r)
                if (ln == 0) sS[(mi * 16 + quad * 4 + r) * 4 + wave] = pv[mi][r];
        __syncthreads();

        float* obase = out + (size_t)(b * NSEL + j) * (LC * LT);
#pragma unroll
        for (int mi = 0; mi < 2; ++mi)
#pragma unroll
            for (int r = 0; r < 4; ++r) {
                int c = mi * 16 + quad * 4 + r;
                float ss = sS[c * 4 + 0] + sS[c * 4 + 1] + sS[c * 4 + 2] + sS[c * 4 + 3];
                float rinv = 1.0f / sqrtf(ss);
                obase[c * LT + wave * 16 + ln] = acc[mi][0][r] * rinv;
            }
    }
}

// ===================== fallback 4-kernel path (R10) ==========================
__global__ __launch_bounds__(256) void k_prep(const int* __restrict__ claim,
                                              const float* __restrict__ emb,
                                              _Float16* __restrict__ tab,
                                              _Float16* __restrict__ wsA,
                                              int tableBlocks) {
    int wave = threadIdx.x >> 6, lane = threadIdx.x & 63;
    if ((int)blockIdx.x < tableBlocks) {
#pragma unroll
        for (int it = 0; it < 8; ++it) {
            int r = blockIdx.x * 32 + it * 4 + wave;
            if (r < VOCAB) {
                const float* src = emb + (size_t)r * D;
                _Float16* d = tab + (size_t)r * TROW;
#pragma unroll
                for (int i = 0; i < 5; ++i) {
                    int k = lane + i * 64;
                    d[k] = (k < D) ? (_Float16)src[k] : (_Float16)0.0f;
                }
            }
        }
    } else {
#pragma unroll
        for (int it = 0; it < 8; ++it) {
            int row = (blockIdx.x - tableBlocks) * 32 + it * 4 + wave;
            int b = row >> 5, m = row & 31;
            int tok = claim[row];
            const float* src = emb + (size_t)tok * D;
            _Float16* base = wsA + (size_t)b * A_HALF;
#pragma unroll
            for (int i = 0; i < 5; ++i) {
                int k = lane + i * 64;
                float x = (k < D) ? src[k] : 0.0f;
                _Float16 h = (_Float16)x;
                int sp = ((k >> 3) ^ (m & 7));
                int idx = (m * 40 + sp) * 8 + (k & 7);
                base[idx] = h;
                base[10240 + idx] = (_Float16)(x - (float)h);
            }
        }
    }
}

template<bool FAST>
__global__ __launch_bounds__(256, 4) void k_scores(const int* __restrict__ targets,
                                                   const float* __restrict__ emb,
                                                   const _Float16* __restrict__ tab,
                                                   const _Float16* __restrict__ wsA,
                                                   float* __restrict__ wsScr) {
    __shared__ __align__(16) uint4 sA[A_U4];
    int wg = blockIdx.x;
    int xcd = wg & 7, rest = wg >> 3;
    int b = xcd * 8 + (rest >> 6);
    int tg = rest & 63;
    int tid = threadIdx.x;
    {
        const uint4* src = (const uint4*)(wsA + (size_t)b * A_HALF);
        for (int i = tid; i < A_U4; i += 256) sA[i] = src[i];
    }
    __syncthreads();

    int lane = tid & 63, wave = tid >> 6;
    int t = tg * 4 + wave;
    const int* trow = targets + ((size_t)b * T_ + t) * LT;

    f32x4 acc[2][4];
    if (FAST) compute_noisy(sA, tab, trow, lane, acc);
    else      compute_exact<4>(sA, emb, trow, 0, lane, acc);
    float tot = score_from_acc(acc);
    if (lane == 0) wsScr[b * T_ + t] = tot;
}

__global__ __launch_bounds__(256) void k_sel(const int* __restrict__ targets,
                                             const float* __restrict__ emb,
                                             const _Float16* __restrict__ wsA,
                                             const float* __restrict__ wsScr,
                                             int* __restrict__ wsCand,
                                             float* __restrict__ wsScoreC) {
    __shared__ __align__(16) uint4 sA[A_U4];
    __shared__ int sCand[NCAND];
    int r = blockIdx.x, b = blockIdx.y, tid = threadIdx.x;
    int lane = tid & 63, wave = tid >> 6;
    if (wave) {
        const uint4* src = (const uint4*)(wsA + (size_t)b * A_HALF);
        for (int i = tid - 64; i < A_U4; i += 192) sA[i] = src[i];
    } else {
        float v[4];
#pragma unroll
        for (int i = 0; i < 4; ++i) v[i] = wsScr[b * T_ + lane + 64 * i];
        for (int s = 0; s < NCAND; ++s) {
            float bv = v[0]; int bi = lane;
#pragma unroll
            for (int i = 1; i < 4; ++i) {
                int idx = lane + 64 * i;
                if (v[i] > bv) { bv = v[i]; bi = idx; }
            }
            for (int off = 32; off > 0; off >>= 1) {
                float ov = __shfl_down(bv, off);
                int   oi = __shfl_down(bi, off);
                if (ov > bv || (ov == bv && oi < bi)) { bv = ov; bi = oi; }
            }
            bi = __shfl(bi, 0);
            if (lane == 0) {
                sCand[s] = bi;
                if (r == 0) wsCand[b * NCAND + s] = bi;
            }
            if ((bi & 63) == lane) v[bi >> 6] = -1e30f;
        }
    }
    __syncthreads();

    int c = r * 4 + wave;
    int t = sCand[c];
    const int* trow = targets + ((size_t)b * T_ + t) * LT;
    f32x4 acc[2][4];
    compute_exact<4>(sA, emb, trow, 0, lane, acc);
    float tot = score_from_acc(acc);
    if (lane == 0) wsScoreC[b * NCAND + c] = tot;
}

__global__ __launch_bounds__(256) void k_output(const int* __restrict__ targets,
                                                const float* __restrict__ emb,
                                                const _Float16* __restrict__ wsA,
                                                const int* __restrict__ wsCand,
                                                const float* __restrict__ wsScoreC,
                                                float* __restrict__ out) {
    __shared__ __align__(16) uint4 sA[A_U4];
    __shared__ float sS[LC][4];
    __shared__ int sT;
    int b = blockIdx.y, j = blockIdx.x, tid = threadIdx.x;
    int lane = tid & 63, wave = tid >> 6;
    if (wave) {
        const uint4* src = (const uint4*)(wsA + (size_t)b * A_HALF);
        for (int i = tid - 64; i < A_U4; i += 192) sA[i] = src[i];
    } else if (lane == 0) {
        unsigned used = 0; int sel = 0;
        for (int jj = 0; jj <= j; ++jj) {
            float bs = -1e30f; int bt = 0x7fffffff, bsl = 0;
            for (int s = 0; s < NCAND; ++s) {
                if (used & (1u << s)) continue;
                float sc = wsScoreC[b * NCAND + s];
                int tt = wsCand[b * NCAND + s];
                if (sc > bs || (sc == bs && tt < bt)) { bs = sc; bt = tt; bsl = s; }
            }
            used |= (1u << bsl);
            sel = bt;
        }
        sT = sel;
    }
    __syncthreads();

    int t = sT;
    const int* trow = targets + ((size_t)b * T_ + t) * LT;
    f32x4 acc[2][1];
    compute_exact<1>(sA, emb, trow, wave * 16, lane, acc);

    int ln = lane & 15, quad = lane >> 4;
#pragma unroll
    for (int mi = 0; mi < 2; ++mi)
#pragma unroll
        for (int r = 0; r < 4; ++r) {
            float v = acc[mi][0][r] * acc[mi][0][r];
            v = xsum4(v);
            if (ln == 0) sS[mi * 16 + quad * 4 + r][wave] = v;
        }
    __syncthreads();

    float* obase = out + (size_t)(b * NSEL + j) * (LC * LT);
#pragma unroll
    for (int mi = 0; mi < 2; ++mi)
#pragma unroll
        for (int r = 0; r < 4; ++r) {
            int c = mi * 16 + quad * 4 + r;
            float ss = sS[c][0] + sS[c][1] + sS[c][2] + sS[c][3];
            float rinv = 1.0f / sqrtf(ss);
            obase[c * LT + wave * 16 + ln] = acc[mi][0][r] * rinv;
        }
}

extern "C" void kernel_launch(void* const* d_in, const int* in_sizes, int n_in,
                              void* d_out, int out_size, void* d_ws, size_t ws_size,
                              hipStream_t stream) {
    const int*   claim   = (const int*)d_in[0];
    const int*   targets = (const int*)d_in[1];
    const float* emb     = (const float*)d_in[2];
    // d_in[3] is n (=5), compile-time NSEL

    const size_t tabBytes = (size_t)VOCAB * TROW * sizeof(_Float16);   // 32 MB
    const size_t restBytes = (size_t)B_ * A_HALF * sizeof(_Float16)
                           + (size_t)B_ * T_ * sizeof(float)
                           + (size_t)B_ * NCAND * (sizeof(int) + sizeof(float)) + 256;
    bool fast = ws_size >= tabBytes + restBytes;   // deterministic per run

    char* p = (char*)d_ws;
    _Float16* tab = nullptr;
    if (fast) { tab = (_Float16*)p; p += tabBytes; }
    _Float16* wsA = (_Float16*)p; p += (size_t)B_ * A_HALF * sizeof(_Float16);
    float* wsScr = (float*)p;     p += (size_t)B_ * T_ * sizeof(float);
    int*   wsCand = (int*)p;      p += (size_t)B_ * NCAND * sizeof(int);
    float* wsScoreC = (float*)p;
    float* out   = (float*)d_out;

    if (fast) {
        // Single fused cooperative kernel (1024 blocks = fully resident).
        // hipLaunchCooperativeKernel validates synchronously -> clean fallback.
        void* args[] = { (void*)&claim, (void*)&targets, (void*)&emb,
                         (void*)&tab, (void*)&wsA, (void*)&wsScr,
                         (void*)&wsCand, (void*)&wsScoreC, (void*)&out };
        hipError_t e = hipLaunchCooperativeKernel((const void*)k_fused,
                                                  dim3(1024), dim3(256),
                                                  args, 0, stream);
        if (e == hipSuccess) return;
        // fall through to the proven 4-kernel path
    }

    int tableBlocks = fast ? ((VOCAB + 31) / 32) : 0;
    k_prep<<<dim3(tableBlocks + 64), dim3(256), 0, stream>>>(claim, emb, tab, wsA, tableBlocks);
    if (fast) {
        k_scores<true><<<dim3(B_ * 64), dim3(256), 0, stream>>>(targets, emb, tab, wsA, wsScr);
    } else {
        k_scores<false><<<dim3(B_ * 64), dim3(256), 0, stream>>>(targets, emb, tab, wsA, wsScr);
    }
    k_sel<<<dim3(NCAND / 4, B_), dim3(256), 0, stream>>>(targets, emb, wsA, wsScr, wsCand, wsScoreC);
    k_output<<<dim3(NSEL, B_), dim3(256), 0, stream>>>(targets, emb, wsA, wsCand, wsScoreC, out);
}

// Round 13
// 488.679 us; speedup vs baseline: 1.4841x; 1.4841x over previous
//
#include <hip/hip_runtime.h>

// Problem constants (fixed by the reference)
#define VOCAB 50000
#define D     300
#define B_    64
#define LC    32
#define T_    256
#define LT    64
#define NSEL  5
#define NCAND 16              // noisy-candidate buffer for exact rescoring

#define A_U4   2560
#define A_HALF 20480
#define TROW   320            // hi-ONLY table row: 320 halfs = 640 B = 10 lines

typedef _Float16 half8_t __attribute__((ext_vector_type(8)));
typedef float    f32x4   __attribute__((ext_vector_type(4)));

// Session ledger:
//  R1/R3: register-spill walls -> 16 waves/CU @ 128 regs for k_scores.
//  R2: setprio +4% cost. R5: serve-rate law dur = FETCH/3.3TB/s (all configs).
//  R7: 64B fill granule. R8: alignment is the table's value.
//  R9: f16-hi selection rows + exact top-16 rescore: k_scores 103us (floor
//      ~89us at the LLC random-64B serve rate). int8/fp8 numerically dead.
//  R10: parallel rescore: 235us total. R11: block-count null.
//  R12: cooperative grid.sync = device-fence L2 FLUSH per phase on 8 XCDs ->
//      FETCH +290MB, WRITE +130MB, 647us. Grid-wide sync is wrong here.
//  R13 (this): last-arriver per-b tail. Each k_scores block: fence + atomic
//      inc cnt[b]; the 64th block rescores top-16 + writes all 5 output tiles
//      inline (in-wave tiles, no extra LDS -> occupancy preserved). 2 kernels.

// ---------------- K0: merged prep: hi-only table + claim images + cnt=0 -----
__global__ __launch_bounds__(256) void k_prep(const int* __restrict__ claim,
                                              const float* __restrict__ emb,
                                              _Float16* __restrict__ tab,
                                              _Float16* __restrict__ wsA,
                                              int* __restrict__ wsCnt,
                                              int tableBlocks) {
    int wave = threadIdx.x >> 6, lane = threadIdx.x & 63;
    if ((int)blockIdx.x == tableBlocks && threadIdx.x < B_) wsCnt[threadIdx.x] = 0;
    if ((int)blockIdx.x < tableBlocks) {
        int r = blockIdx.x * 4 + wave;               // 12500*4 = 50000 rows
        const float* src = emb + (size_t)r * D;
        _Float16* d = tab + (size_t)r * TROW;
#pragma unroll
        for (int i = 0; i < 5; ++i) {
            int k = lane + i * 64;
            d[k] = (k < D) ? (_Float16)src[k] : (_Float16)0.0f;
        }
    } else {
        int row = (blockIdx.x - tableBlocks) * 4 + wave;   // 0..2047
        int b = row >> 5, m = row & 31;
        int tok = claim[row];
        const float* src = emb + (size_t)tok * D;
        _Float16* base = wsA + (size_t)b * A_HALF;
#pragma unroll
        for (int i = 0; i < 5; ++i) {
            int k = lane + i * 64;
            float x = (k < D) ? src[k] : 0.0f;
            _Float16 h = (_Float16)x;
            int sp = ((k >> 3) ^ (m & 7));
            int idx = (m * 40 + sp) * 8 + (k & 7);
            base[idx] = h;
            base[10240 + idx] = (_Float16)(x - (float)h);
        }
    }
}

// hi/lo split of a float4 pair into half8 hi and half8 lo (exact path)
__device__ __forceinline__ void split8(const float4& a, const float4& b,
                                       half8_t& hv, half8_t& lv) {
    float x[8] = {a.x, a.y, a.z, a.w, b.x, b.y, b.z, b.w};
#pragma unroll
    for (int i = 0; i < 8; ++i) {
        _Float16 h = (_Float16)x[i];
        hv[i] = h;
        lv[i] = (_Float16)(x[i] - (float)h);
    }
}

// ---------------- exact K-loop (f32 emb gather + on-the-fly split) -----------
template<int NI>
__device__ __forceinline__ void compute_exact(const uint4* sA,
                                              const float* __restrict__ emb,
                                              const int* __restrict__ trow, int lcol0,
                                              int lane, f32x4 acc[2][NI]) {
    int ln = lane & 15, quad = lane >> 4;
#pragma unroll
    for (int mi = 0; mi < 2; ++mi)
#pragma unroll
        for (int ni = 0; ni < NI; ++ni) acc[mi][ni] = (f32x4)0.0f;

    int arow0 = ln * 40;
    int arow1 = (16 + ln) * 40;
    int key = ln & 7;
    int qo = quad * 8;

    const float* bp[NI];
#pragma unroll
    for (int ni = 0; ni < NI; ++ni) {
        int tok = trow[lcol0 + ni * 16 + ln];
        bp[ni] = emb + (size_t)tok * D;
    }
#pragma unroll 1
    for (int ks = 0; ks < 10; ++ks) {
        int kb = ks * 32 + qo;
        int ka = kb > 296 ? 296 : kb;
        int kb4 = kb + 4;
        int kbb = kb4 > 296 ? 296 : kb4;
        float4 b0[NI], b1[NI];
#pragma unroll
        for (int ni = 0; ni < NI; ++ni) {
            b0[ni] = *(const float4*)(bp[ni] + ka);
            b1[ni] = *(const float4*)(bp[ni] + kbb);
        }
        if (kb >= 296) {
            float4 z = make_float4(0.f, 0.f, 0.f, 0.f);
#pragma unroll
            for (int ni = 0; ni < NI; ++ni) {
                if (kb >= 300) b0[ni] = z;
                b1[ni] = z;
            }
        }
        int sp = (ks * 4 + quad) ^ key;
        half8_t ah[2], al[2];
        ah[0] = __builtin_bit_cast(half8_t, sA[arow0 + sp]);
        al[0] = __builtin_bit_cast(half8_t, sA[1280 + arow0 + sp]);
        ah[1] = __builtin_bit_cast(half8_t, sA[arow1 + sp]);
        al[1] = __builtin_bit_cast(half8_t, sA[1280 + arow1 + sp]);
        half8_t bh[NI], bl[NI];
#pragma unroll
        for (int ni = 0; ni < NI; ++ni) split8(b0[ni], b1[ni], bh[ni], bl[ni]);
#pragma unroll
        for (int mi = 0; mi < 2; ++mi)
#pragma unroll
            for (int ni = 0; ni < NI; ++ni) {
                acc[mi][ni] = __builtin_amdgcn_mfma_f32_16x16x32_f16(ah[mi], bh[ni], acc[mi][ni], 0, 0, 0);
                acc[mi][ni] = __builtin_amdgcn_mfma_f32_16x16x32_f16(ah[mi], bl[ni], acc[mi][ni], 0, 0, 0);
                acc[mi][ni] = __builtin_amdgcn_mfma_f32_16x16x32_f16(al[mi], bh[ni], acc[mi][ni], 0, 0, 0);
            }
    }
}

// ---------------- noisy K-loop (hi-only 640B table rows, selection only) -----
__device__ __forceinline__ void compute_noisy(const uint4* sA,
                                              const _Float16* __restrict__ tab,
                                              const int* __restrict__ trow,
                                              int lane, f32x4 acc[2][4]) {
    int ln = lane & 15, quad = lane >> 4;
#pragma unroll
    for (int mi = 0; mi < 2; ++mi)
#pragma unroll
        for (int ni = 0; ni < 4; ++ni) acc[mi][ni] = (f32x4)0.0f;

    int arow0 = ln * 40;
    int arow1 = (16 + ln) * 40;
    int key = ln & 7;
    int qo = quad * 8;

    const _Float16* rp[4];
#pragma unroll
    for (int ni = 0; ni < 4; ++ni) {
        int tok = trow[ni * 16 + ln];
        rp[ni] = tab + (size_t)tok * TROW;
    }
    half8_t bh[2][4];
#pragma unroll
    for (int ni = 0; ni < 4; ++ni) bh[0][ni] = *(const half8_t*)(rp[ni] + qo);
#pragma unroll
    for (int ks = 0; ks < 10; ++ks) {
        int cur = ks & 1, nxt = cur ^ 1;
        if (ks < 9) {
            int ko = (ks + 1) * 32 + qo;
#pragma unroll
            for (int ni = 0; ni < 4; ++ni)
                bh[nxt][ni] = *(const half8_t*)(rp[ni] + ko);
        }
        int sp = (ks * 4 + quad) ^ key;
        half8_t ah[2], al[2];
        ah[0] = __builtin_bit_cast(half8_t, sA[arow0 + sp]);
        al[0] = __builtin_bit_cast(half8_t, sA[1280 + arow0 + sp]);
        ah[1] = __builtin_bit_cast(half8_t, sA[arow1 + sp]);
        al[1] = __builtin_bit_cast(half8_t, sA[1280 + arow1 + sp]);
#pragma unroll
        for (int mi = 0; mi < 2; ++mi)
#pragma unroll
            for (int ni = 0; ni < 4; ++ni) {
                acc[mi][ni] = __builtin_amdgcn_mfma_f32_16x16x32_f16(ah[mi], bh[cur][ni], acc[mi][ni], 0, 0, 0);
                acc[mi][ni] = __builtin_amdgcn_mfma_f32_16x16x32_f16(al[mi], bh[cur][ni], acc[mi][ni], 0, 0, 0);
            }
    }
}

__device__ __forceinline__ float xmax4(float v) {
    v = fmaxf(v, __shfl_xor(v, 1)); v = fmaxf(v, __shfl_xor(v, 2));
    v = fmaxf(v, __shfl_xor(v, 4)); v = fmaxf(v, __shfl_xor(v, 8));
    return v;
}
__device__ __forceinline__ float xsum4(float v) {
    v += __shfl_xor(v, 1); v += __shfl_xor(v, 2);
    v += __shfl_xor(v, 4); v += __shfl_xor(v, 8);
    return v;
}

// target score from a wave's acc[2][4] — op order identical to R0..R12.
__device__ __forceinline__ float score_from_acc(f32x4 acc[2][4]) {
    float score_l[4] = {0.f, 0.f, 0.f, 0.f};
#pragma unroll
    for (int mi = 0; mi < 2; ++mi)
#pragma unroll
        for (int r = 0; r < 4; ++r) {
            float m = fmaxf(fmaxf(acc[mi][0][r], acc[mi][1][r]),
                            fmaxf(acc[mi][2][r], acc[mi][3][r]));
            m = xmax4(m);
            float p[4], s = 0.f;
#pragma unroll
            for (int ni = 0; ni < 4; ++ni) { p[ni] = __expf(acc[mi][ni][r] - m); s += p[ni]; }
            s = xsum4(s);
            float rv = 1.0f / s;
#pragma unroll
            for (int ni = 0; ni < 4; ++ni) score_l[ni] = fmaxf(score_l[ni], p[ni] * rv);
        }
    float tot = 0.f;
#pragma unroll
    for (int ni = 0; ni < 4; ++ni) {
        float v = score_l[ni];
        v = fmaxf(v, __shfl_xor(v, 16));
        v = fmaxf(v, __shfl_xor(v, 32));
        tot += v;
    }
    return xsum4(tot);
}

// ---------------- K1: scores + last-arriver selection/output tail ------------
// Grid 4096, XCD swizzle as before. After scoring, each block: release fence +
// atomicAdd(cnt[b]); the 64th arriver (sA already staged) rescores the noisy
// top-16 exactly and writes all 5 normalized output tiles in-wave.
template<bool FAST>
__global__ __launch_bounds__(256, 4) void k_scores(const int* __restrict__ targets,
                                                   const float* __restrict__ emb,
                                                   const _Float16* __restrict__ tab,
                                                   const _Float16* __restrict__ wsA,
                                                   float* __restrict__ wsScr,
                                                   int* __restrict__ wsCand,
                                                   float* __restrict__ wsScoreC,
                                                   int* __restrict__ wsCnt,
                                                   int* __restrict__ wsFlag,
                                                   float* __restrict__ out) {
    __shared__ __align__(16) uint4 sA[A_U4];   // 40960 B exactly -> 4 blocks/CU
    int wg = blockIdx.x;
    int xcd = wg & 7, rest = wg >> 3;
    int b = xcd * 8 + (rest >> 6);
    int tg = rest & 63;
    int tid = threadIdx.x;
    {
        const uint4* src = (const uint4*)(wsA + (size_t)b * A_HALF);
        for (int i = tid; i < A_U4; i += 256) sA[i] = src[i];
    }
    __syncthreads();

    int lane = tid & 63, wave = tid >> 6;
    int t = tg * 4 + wave;
    const int* trow = targets + ((size_t)b * T_ + t) * LT;

    {
        f32x4 acc[2][4];
        if (FAST) compute_noisy(sA, tab, trow, lane, acc);
        else      compute_exact<4>(sA, emb, trow, 0, lane, acc);
        float tot = score_from_acc(acc);
        if (lane == 0) wsScr[b * T_ + t] = tot;
    }

    // ---- last-arriver handoff (G16: device-scope fence + atomic) -----------
    __syncthreads();                     // all 4 score stores drained (vmcnt)
    if (tid == 0) {
        __threadfence();                 // release: scores -> device scope
        int prev = atomicAdd(&wsCnt[b], 1);
        wsFlag[wg] = (prev == B_ - 1);   // 64 blocks per b
    }
    __syncthreads();                     // flag store drained before read
    if (!wsFlag[wg]) return;
    __threadfence();                     // acquire: drop stale cached wsScr

    // ---- noisy top-16 replay (wave 0; rules identical to R10/R12) ----------
    if (wave == 0) {
        float v[4];
#pragma unroll
        for (int i = 0; i < 4; ++i) v[i] = wsScr[b * T_ + lane + 64 * i];
#pragma unroll
        for (int s = 0; s < NCAND; ++s) {
            float bv = v[0]; int bi = lane;
#pragma unroll
            for (int i = 1; i < 4; ++i) {
                int idx = lane + 64 * i;
                if (v[i] > bv) { bv = v[i]; bi = idx; }
            }
            for (int off = 32; off > 0; off >>= 1) {
                float ov = __shfl_down(bv, off);
                int   oi = __shfl_down(bi, off);
                if (ov > bv || (ov == bv && oi < bi)) { bv = ov; bi = oi; }
            }
            bi = __shfl(bi, 0);
            if (lane == 0) wsCand[b * NCAND + s] = bi;
            if ((bi & 63) == lane) v[bi >> 6] = -1e30f;
        }
    }
    __syncthreads();                     // wsCand visible (same CU)

    // ---- exact rescore: wave w does candidates p*4+w, p=0..3 ---------------
#pragma unroll 1
    for (int p = 0; p < 4; ++p) {
        int tc = wsCand[b * NCAND + p * 4 + wave];
        const int* tr = targets + ((size_t)b * T_ + tc) * LT;
        f32x4 a2[2][4];
        compute_exact<4>(sA, emb, tr, 0, lane, a2);
        float sc = score_from_acc(a2);
        if (lane == 0) wsScoreC[b * NCAND + p * 4 + wave] = sc;
    }
    __syncthreads();                     // wsScoreC visible (same CU)

    // ---- output tiles, fully in-wave: wave w does j = w, w+4 ---------------
    int ln = lane & 15, quad = lane >> 4;
#pragma unroll 1
    for (int j = wave; j < NSEL; j += 4) {
        // exact rank-j selection from the 16 (cand,score) pairs (R10 rules)
        unsigned used = 0; int sel = 0;
        for (int jj = 0; jj <= j; ++jj) {
            float bs = -1e30f; int bt = 0x7fffffff, bsl = 0;
            for (int s = 0; s < NCAND; ++s) {
                if (used & (1u << s)) continue;
                float sc = wsScoreC[b * NCAND + s];
                int tt = wsCand[b * NCAND + s];
                if (sc > bs || (sc == bs && tt < bt)) { bs = sc; bt = tt; bsl = s; }
            }
            used |= (1u << bsl);
            sel = bt;
        }
        const int* tr = targets + ((size_t)b * T_ + sel) * LT;
        f32x4 a2[2][4];
        compute_exact<4>(sA, emb, tr, 0, lane, a2);   // full 32x64 tile in-wave
        float* obase = out + (size_t)(b * NSEL + j) * (LC * LT);
#pragma unroll
        for (int mi = 0; mi < 2; ++mi)
#pragma unroll
            for (int r = 0; r < 4; ++r) {
                float ssum = 0.f;
#pragma unroll
                for (int ni = 0; ni < 4; ++ni) ssum += a2[mi][ni][r] * a2[mi][ni][r];
                ssum = xsum4(ssum);                   // sum over all 64 l
                float rinv = 1.0f / sqrtf(ssum);
                int c = mi * 16 + quad * 4 + r;
#pragma unroll
                for (int ni = 0; ni < 4; ++ni)
                    obase[c * LT + ni * 16 + ln] = a2[mi][ni][r] * rinv;
            }
    }
}

extern "C" void kernel_launch(void* const* d_in, const int* in_sizes, int n_in,
                              void* d_out, int out_size, void* d_ws, size_t ws_size,
                              hipStream_t stream) {
    const int*   claim   = (const int*)d_in[0];
    const int*   targets = (const int*)d_in[1];
    const float* emb     = (const float*)d_in[2];
    // d_in[3] is n (=5), compile-time NSEL

    const size_t tabBytes = (size_t)VOCAB * TROW * sizeof(_Float16);   // 32 MB
    const size_t restBytes = (size_t)B_ * A_HALF * sizeof(_Float16)
                           + (size_t)B_ * T_ * sizeof(float)
                           + (size_t)B_ * NCAND * (sizeof(int) + sizeof(float))
                           + B_ * sizeof(int) + 4096 * sizeof(int) + 256;
    bool fast = ws_size >= tabBytes + restBytes;   // deterministic per run

    char* p = (char*)d_ws;
    _Float16* tab = nullptr;
    if (fast) { tab = (_Float16*)p; p += tabBytes; }
    _Float16* wsA = (_Float16*)p;  p += (size_t)B_ * A_HALF * sizeof(_Float16);
    float* wsScr = (float*)p;      p += (size_t)B_ * T_ * sizeof(float);
    int*   wsCand = (int*)p;       p += (size_t)B_ * NCAND * sizeof(int);
    float* wsScoreC = (float*)p;   p += (size_t)B_ * NCAND * sizeof(float);
    int*   wsCnt = (int*)p;        p += B_ * sizeof(int);
    int*   wsFlag = (int*)p;
    float* out   = (float*)d_out;

    int tableBlocks = fast ? (VOCAB / 4) : 0;
    k_prep<<<dim3(tableBlocks + 512), dim3(256), 0, stream>>>(claim, emb, tab, wsA, wsCnt, tableBlocks);
    if (fast) {
        k_scores<true><<<dim3(B_ * 64), dim3(256), 0, stream>>>(
            targets, emb, tab, wsA, wsScr, wsCand, wsScoreC, wsCnt, wsFlag, out);
    } else {
        k_scores<false><<<dim3(B_ * 64), dim3(256), 0, stream>>>(
            targets, emb, tab, wsA, wsScr, wsCand, wsScoreC, wsCnt, wsFlag, out);
    }
}

// Round 14
// 254.461 us; speedup vs baseline: 2.8501x; 1.9204x over previous
//
#include <hip/hip_runtime.h>

// Problem constants (fixed by the reference)
#define VOCAB 50000
#define D     300
#define B_    64
#define LC    32
#define T_    256
#define LT    64
#define NSEL  5
#define NCAND 16              // noisy-candidate buffer for exact rescoring

#define A_U4   2560
#define A_HALF 20480
#define TROW   320            // hi-ONLY table row: 320 halfs = 640 B = 10 lines

typedef _Float16 half8_t __attribute__((ext_vector_type(8)));
typedef float    f32x4   __attribute__((ext_vector_type(4)));

// Session ledger:
//  R1/R3: register-spill walls -> 16 waves/CU @ 128 regs for k_scores.
//  R2: setprio +4%. R5: serve-rate law dur = FETCH/3.3TB/s (all configs).
//  R7: 64B fill granule. R8: alignment is the table's value.
//  R9: f16-hi selection rows + exact top-16 rescore: k_scores 103us
//      (floor ~89us, LLC random-64B serve rate). int8/fp8 numerically dead.
//  R10: parallel rescore, 4 kernels: 235us = session best.
//  R12: grid.sync = per-phase L2 FLUSH on 8 XCDs -> 647us. Dead end.
//  R13: per-block __threadfence = per-block L2 writeback walk, 4096x
//      serialized -> BW 893GB/s, 488us. Kernel-launch boundary is the ONLY
//      cheap device-scope fence.
//  R14 (this): R10 structure, but k_sel+k_output merged into ONE per-b
//      kernel (64 blocks x 512 thr, launch-boundary fencing, no atomics).
//      Tail serial depth 2 rescores + 1 tile per wave. 3 dispatches total.
//      Arithmetic forms all previously validated: absmax must stay 2^-10.

// ---------------- K0: merged prep: hi-only table + claim images --------------
__global__ __launch_bounds__(256) void k_prep(const int* __restrict__ claim,
                                              const float* __restrict__ emb,
                                              _Float16* __restrict__ tab,
                                              _Float16* __restrict__ wsA,
                                              int tableBlocks) {
    int wave = threadIdx.x >> 6, lane = threadIdx.x & 63;
    if ((int)blockIdx.x < tableBlocks) {
        int r = blockIdx.x * 4 + wave;               // 12500*4 = 50000 rows
        const float* src = emb + (size_t)r * D;
        _Float16* d = tab + (size_t)r * TROW;
#pragma unroll
        for (int i = 0; i < 5; ++i) {
            int k = lane + i * 64;
            d[k] = (k < D) ? (_Float16)src[k] : (_Float16)0.0f;
        }
    } else {
        int row = (blockIdx.x - tableBlocks) * 4 + wave;   // 0..2047
        int b = row >> 5, m = row & 31;
        int tok = claim[row];
        const float* src = emb + (size_t)tok * D;
        _Float16* base = wsA + (size_t)b * A_HALF;
#pragma unroll
        for (int i = 0; i < 5; ++i) {
            int k = lane + i * 64;
            float x = (k < D) ? src[k] : 0.0f;
            _Float16 h = (_Float16)x;
            int sp = ((k >> 3) ^ (m & 7));
            int idx = (m * 40 + sp) * 8 + (k & 7);
            base[idx] = h;
            base[10240 + idx] = (_Float16)(x - (float)h);
        }
    }
}

// hi/lo split of a float4 pair into half8 hi and half8 lo (exact path)
__device__ __forceinline__ void split8(const float4& a, const float4& b,
                                       half8_t& hv, half8_t& lv) {
    float x[8] = {a.x, a.y, a.z, a.w, b.x, b.y, b.z, b.w};
#pragma unroll
    for (int i = 0; i < 8; ++i) {
        _Float16 h = (_Float16)x[i];
        hv[i] = h;
        lv[i] = (_Float16)(x[i] - (float)h);
    }
}

// ---------------- exact K-loop (f32 emb gather + on-the-fly split) -----------
template<int NI>
__device__ __forceinline__ void compute_exact(const uint4* sA,
                                              const float* __restrict__ emb,
                                              const int* __restrict__ trow, int lcol0,
                                              int lane, f32x4 acc[2][NI]) {
    int ln = lane & 15, quad = lane >> 4;
#pragma unroll
    for (int mi = 0; mi < 2; ++mi)
#pragma unroll
        for (int ni = 0; ni < NI; ++ni) acc[mi][ni] = (f32x4)0.0f;

    int arow0 = ln * 40;
    int arow1 = (16 + ln) * 40;
    int key = ln & 7;
    int qo = quad * 8;

    const float* bp[NI];
#pragma unroll
    for (int ni = 0; ni < NI; ++ni) {
        int tok = trow[lcol0 + ni * 16 + ln];
        bp[ni] = emb + (size_t)tok * D;
    }
#pragma unroll 1
    for (int ks = 0; ks < 10; ++ks) {
        int kb = ks * 32 + qo;
        int ka = kb > 296 ? 296 : kb;
        int kb4 = kb + 4;
        int kbb = kb4 > 296 ? 296 : kb4;
        float4 b0[NI], b1[NI];
#pragma unroll
        for (int ni = 0; ni < NI; ++ni) {
            b0[ni] = *(const float4*)(bp[ni] + ka);
            b1[ni] = *(const float4*)(bp[ni] + kbb);
        }
        if (kb >= 296) {
            float4 z = make_float4(0.f, 0.f, 0.f, 0.f);
#pragma unroll
            for (int ni = 0; ni < NI; ++ni) {
                if (kb >= 300) b0[ni] = z;
                b1[ni] = z;
            }
        }
        int sp = (ks * 4 + quad) ^ key;
        half8_t ah[2], al[2];
        ah[0] = __builtin_bit_cast(half8_t, sA[arow0 + sp]);
        al[0] = __builtin_bit_cast(half8_t, sA[1280 + arow0 + sp]);
        ah[1] = __builtin_bit_cast(half8_t, sA[arow1 + sp]);
        al[1] = __builtin_bit_cast(half8_t, sA[1280 + arow1 + sp]);
        half8_t bh[NI], bl[NI];
#pragma unroll
        for (int ni = 0; ni < NI; ++ni) split8(b0[ni], b1[ni], bh[ni], bl[ni]);
#pragma unroll
        for (int mi = 0; mi < 2; ++mi)
#pragma unroll
            for (int ni = 0; ni < NI; ++ni) {
                acc[mi][ni] = __builtin_amdgcn_mfma_f32_16x16x32_f16(ah[mi], bh[ni], acc[mi][ni], 0, 0, 0);
                acc[mi][ni] = __builtin_amdgcn_mfma_f32_16x16x32_f16(ah[mi], bl[ni], acc[mi][ni], 0, 0, 0);
                acc[mi][ni] = __builtin_amdgcn_mfma_f32_16x16x32_f16(al[mi], bh[ni], acc[mi][ni], 0, 0, 0);
            }
    }
}

// ---------------- noisy K-loop (hi-only 640B table rows, selection only) -----
__device__ __forceinline__ void compute_noisy(const uint4* sA,
                                              const _Float16* __restrict__ tab,
                                              const int* __restrict__ trow,
                                              int lane, f32x4 acc[2][4]) {
    int ln = lane & 15, quad = lane >> 4;
#pragma unroll
    for (int mi = 0; mi < 2; ++mi)
#pragma unroll
        for (int ni = 0; ni < 4; ++ni) acc[mi][ni] = (f32x4)0.0f;

    int arow0 = ln * 40;
    int arow1 = (16 + ln) * 40;
    int key = ln & 7;
    int qo = quad * 8;

    const _Float16* rp[4];
#pragma unroll
    for (int ni = 0; ni < 4; ++ni) {
        int tok = trow[ni * 16 + ln];
        rp[ni] = tab + (size_t)tok * TROW;
    }
    half8_t bh[2][4];
#pragma unroll
    for (int ni = 0; ni < 4; ++ni) bh[0][ni] = *(const half8_t*)(rp[ni] + qo);
#pragma unroll
    for (int ks = 0; ks < 10; ++ks) {
        int cur = ks & 1, nxt = cur ^ 1;
        if (ks < 9) {
            int ko = (ks + 1) * 32 + qo;
#pragma unroll
            for (int ni = 0; ni < 4; ++ni)
                bh[nxt][ni] = *(const half8_t*)(rp[ni] + ko);
        }
        int sp = (ks * 4 + quad) ^ key;
        half8_t ah[2], al[2];
        ah[0] = __builtin_bit_cast(half8_t, sA[arow0 + sp]);
        al[0] = __builtin_bit_cast(half8_t, sA[1280 + arow0 + sp]);
        ah[1] = __builtin_bit_cast(half8_t, sA[arow1 + sp]);
        al[1] = __builtin_bit_cast(half8_t, sA[1280 + arow1 + sp]);
#pragma unroll
        for (int mi = 0; mi < 2; ++mi)
#pragma unroll
            for (int ni = 0; ni < 4; ++ni) {
                acc[mi][ni] = __builtin_amdgcn_mfma_f32_16x16x32_f16(ah[mi], bh[cur][ni], acc[mi][ni], 0, 0, 0);
                acc[mi][ni] = __builtin_amdgcn_mfma_f32_16x16x32_f16(al[mi], bh[cur][ni], acc[mi][ni], 0, 0, 0);
            }
    }
}

__device__ __forceinline__ float xmax4(float v) {
    v = fmaxf(v, __shfl_xor(v, 1)); v = fmaxf(v, __shfl_xor(v, 2));
    v = fmaxf(v, __shfl_xor(v, 4)); v = fmaxf(v, __shfl_xor(v, 8));
    return v;
}
__device__ __forceinline__ float xsum4(float v) {
    v += __shfl_xor(v, 1); v += __shfl_xor(v, 2);
    v += __shfl_xor(v, 4); v += __shfl_xor(v, 8);
    return v;
}

// target score from a wave's acc[2][4] — op order identical to R0..R13.
__device__ __forceinline__ float score_from_acc(f32x4 acc[2][4]) {
    float score_l[4] = {0.f, 0.f, 0.f, 0.f};
#pragma unroll
    for (int mi = 0; mi < 2; ++mi)
#pragma unroll
        for (int r = 0; r < 4; ++r) {
            float m = fmaxf(fmaxf(acc[mi][0][r], acc[mi][1][r]),
                            fmaxf(acc[mi][2][r], acc[mi][3][r]));
            m = xmax4(m);
            float p[4], s = 0.f;
#pragma unroll
            for (int ni = 0; ni < 4; ++ni) { p[ni] = __expf(acc[mi][ni][r] - m); s += p[ni]; }
            s = xsum4(s);
            float rv = 1.0f / s;
#pragma unroll
            for (int ni = 0; ni < 4; ++ni) score_l[ni] = fmaxf(score_l[ni], p[ni] * rv);
        }
    float tot = 0.f;
#pragma unroll
    for (int ni = 0; ni < 4; ++ni) {
        float v = score_l[ni];
        v = fmaxf(v, __shfl_xor(v, 16));
        v = fmaxf(v, __shfl_xor(v, 32));
        tot += v;
    }
    return xsum4(tot);
}

// ---------------- K1: noisy target scores (wave-per-t; XCD swizzle) ----------
template<bool FAST>
__global__ __launch_bounds__(256, 4) void k_scores(const int* __restrict__ targets,
                                                   const float* __restrict__ emb,
                                                   const _Float16* __restrict__ tab,
                                                   const _Float16* __restrict__ wsA,
                                                   float* __restrict__ wsScr) {
    __shared__ __align__(16) uint4 sA[A_U4];   // 40960 B -> 4 blocks/CU
    int wg = blockIdx.x;
    int xcd = wg & 7, rest = wg >> 3;
    int b = xcd * 8 + (rest >> 6);
    int tg = rest & 63;
    int tid = threadIdx.x;
    {
        const uint4* src = (const uint4*)(wsA + (size_t)b * A_HALF);
        for (int i = tid; i < A_U4; i += 256) sA[i] = src[i];
    }
    __syncthreads();

    int lane = tid & 63, wave = tid >> 6;
    int t = tg * 4 + wave;
    const int* trow = targets + ((size_t)b * T_ + t) * LT;

    f32x4 acc[2][4];
    if (FAST) compute_noisy(sA, tab, trow, lane, acc);
    else      compute_exact<4>(sA, emb, trow, 0, lane, acc);
    float tot = score_from_acc(acc);
    if (lane == 0) wsScr[b * T_ + t] = tot;
}

// ---------------- K2: fused selection tail (one block per b, 8 waves) -------
// Wave 0 replays the noisy top-16 (rules identical to R10) while waves 1..7
// stage sA. Then wave w exactly rescores candidates w and w+8 (serial depth
// 2); waves 0..4 each compute one output tile fully in-wave (R13-validated
// form) and write it L2-normalized. Launch-boundary fencing only.
__global__ __launch_bounds__(512, 2) void k_tail(const int* __restrict__ targets,
                                                 const float* __restrict__ emb,
                                                 const _Float16* __restrict__ wsA,
                                                 const float* __restrict__ wsScr,
                                                 float* __restrict__ out) {
    __shared__ __align__(16) uint4 sA[A_U4];
    __shared__ int sCand[NCAND];
    __shared__ float sScore[NCAND];
    int b = blockIdx.x, tid = threadIdx.x;
    int lane = tid & 63, wave = tid >> 6;          // 8 waves

    if (wave) {                                    // waves 1..7 stage sA
        const uint4* src = (const uint4*)(wsA + (size_t)b * A_HALF);
        for (int i = tid - 64; i < A_U4; i += 448) sA[i] = src[i];
    } else {                                       // wave 0: noisy top-16
        float v[4];
#pragma unroll
        for (int i = 0; i < 4; ++i) v[i] = wsScr[b * T_ + lane + 64 * i];
#pragma unroll
        for (int s = 0; s < NCAND; ++s) {
            float bv = v[0]; int bi = lane;
#pragma unroll
            for (int i = 1; i < 4; ++i) {
                int idx = lane + 64 * i;
                if (v[i] > bv) { bv = v[i]; bi = idx; }
            }
            for (int off = 32; off > 0; off >>= 1) {
                float ov = __shfl_down(bv, off);
                int   oi = __shfl_down(bi, off);
                if (ov > bv || (ov == bv && oi < bi)) { bv = ov; bi = oi; }
            }
            bi = __shfl(bi, 0);
            if (lane == 0) sCand[s] = bi;
            if ((bi & 63) == lane) v[bi >> 6] = -1e30f;
        }
    }
    __syncthreads();

    // exact rescore: wave w does candidates w and w+8
#pragma unroll 1
    for (int p = 0; p < 2; ++p) {
        int c = wave + p * 8;
        int t = sCand[c];
        const int* tr = targets + ((size_t)b * T_ + t) * LT;
        f32x4 a2[2][4];
        compute_exact<4>(sA, emb, tr, 0, lane, a2);
        float sc = score_from_acc(a2);
        if (lane == 0) sScore[c] = sc;
    }
    __syncthreads();

    // output tiles: wave j (j<5) computes rank-j tile fully in-wave
    if (wave < NSEL) {
        int j = wave;
        unsigned used = 0; int sel = 0;
        for (int jj = 0; jj <= j; ++jj) {
            float bs = -1e30f; int bt = 0x7fffffff, bsl = 0;
            for (int s = 0; s < NCAND; ++s) {
                if (used & (1u << s)) continue;
                float sc = sScore[s]; int tt = sCand[s];
                if (sc > bs || (sc == bs && tt < bt)) { bs = sc; bt = tt; bsl = s; }
            }
            used |= (1u << bsl);
            sel = bt;
        }
        const int* tr = targets + ((size_t)b * T_ + sel) * LT;
        f32x4 a2[2][4];
        compute_exact<4>(sA, emb, tr, 0, lane, a2);   // full 32x64 tile in-wave
        int ln = lane & 15, quad = lane >> 4;
        float* obase = out + (size_t)(b * NSEL + j) * (LC * LT);
#pragma unroll
        for (int mi = 0; mi < 2; ++mi)
#pragma unroll
            for (int r = 0; r < 4; ++r) {
                float ssum = 0.f;
#pragma unroll
                for (int ni = 0; ni < 4; ++ni) ssum += a2[mi][ni][r] * a2[mi][ni][r];
                ssum = xsum4(ssum);                   // sum over all 64 l
                float rinv = 1.0f / sqrtf(ssum);
                int c = mi * 16 + quad * 4 + r;
#pragma unroll
                for (int ni = 0; ni < 4; ++ni)
                    obase[c * LT + ni * 16 + ln] = a2[mi][ni][r] * rinv;
            }
    }
}

extern "C" void kernel_launch(void* const* d_in, const int* in_sizes, int n_in,
                              void* d_out, int out_size, void* d_ws, size_t ws_size,
                              hipStream_t stream) {
    const int*   claim   = (const int*)d_in[0];
    const int*   targets = (const int*)d_in[1];
    const float* emb     = (const float*)d_in[2];
    // d_in[3] is n (=5), compile-time NSEL

    const size_t tabBytes = (size_t)VOCAB * TROW * sizeof(_Float16);   // 32 MB
    const size_t restBytes = (size_t)B_ * A_HALF * sizeof(_Float16)
                           + (size_t)B_ * T_ * sizeof(float) + 256;
    bool fast = ws_size >= tabBytes + restBytes;   // deterministic per run

    char* p = (char*)d_ws;
    _Float16* tab = nullptr;
    if (fast) { tab = (_Float16*)p; p += tabBytes; }
    _Float16* wsA = (_Float16*)p;  p += (size_t)B_ * A_HALF * sizeof(_Float16);
    float* wsScr = (float*)p;
    float* out   = (float*)d_out;

    int tableBlocks = fast ? (VOCAB / 4) : 0;
    k_prep<<<dim3(tableBlocks + 512), dim3(256), 0, stream>>>(claim, emb, tab, wsA, tableBlocks);
    if (fast) {
        k_scores<true><<<dim3(B_ * 64), dim3(256), 0, stream>>>(targets, emb, tab, wsA, wsScr);
    } else {
        k_scores<false><<<dim3(B_ * 64), dim3(256), 0, stream>>>(targets, emb, tab, wsA, wsScr);
    }
    k_tail<<<dim3(B_), dim3(512), 0, stream>>>(targets, emb, wsA, wsScr, out);
}